// Round 2
// baseline (242.850 us; speedup 1.0000x reference)
//
#include <hip/hip_runtime.h>
#include <hip/hip_bf16.h>

#define BATCH 8
#define CIN 256
#define CD 128
#define NPIX 4096  // 64*64

typedef __attribute__((ext_vector_type(4))) float f32x4;
typedef __attribute__((ext_vector_type(8))) short s16x8;
typedef __attribute__((ext_vector_type(4))) short s16x4;

__device__ __forceinline__ short f2bf(float f) {
  union { float f; unsigned u; } v; v.f = f;
  unsigned r = v.u + 0x7fffu + ((v.u >> 16) & 1u);
  return (short)(r >> 16);
}
__device__ __forceinline__ float bf2f(short s) {
  union { unsigned u; float f; } v; v.u = ((unsigned)(unsigned short)s) << 16;
  return v.f;
}

#define MFMA(a, b, c) __builtin_amdgcn_mfma_f32_16x16x32_bf16((a), (b), (c), 0, 0, 0)

// ---------------------------------------------------------------- kernel 0
// Convert all weight matrices to bf16 once. Layout in ws: Wq,Wk,Wv,Wt,Wf
// contiguous, each row-major as in the inputs.
__global__ void k_wconv(const float* __restrict__ Wq, const float* __restrict__ Wk,
                        const float* __restrict__ Wv, const float* __restrict__ Wt,
                        const float* __restrict__ Wf, short* __restrict__ out) {
  int idx = blockIdx.x * 256 + threadIdx.x;  // 0..163839
  int region = idx >> 15;                    // uniform per block (32768/256=128 blocks per region)
  const float* src = (region == 0) ? Wq : (region == 1) ? Wk : (region == 2) ? Wv
                     : (region == 3) ? Wt : Wf;
  out[idx] = f2bf(src[idx & 32767]);
}

// ---------------------------------------------------------------- kernel 1
// QKVT projection. Block = 512 thr (8 waves), grid = B * 64 n-tiles.
// LDS holds feat_t / feat_i tiles TRANSPOSED to [n][c] bf16 (XOR-swizzled at
// 16B granularity so ds_read_b128 fragment reads are conflict-free).
// Waves 0/1: Q lo/hi (A=X_t^T, B=Wq rows)  -> Qb[b][n][cd], pre-scaled 1/sqrt(128)
// Waves 2/3: K lo/hi                       -> Kb[b][n][cd]
// Waves 4/5: V lo/hi (A=Wv rows, B=X_i^T)  -> Vb[b][cd][n]
// Waves 6/7: T lo/hi                       -> Tb[b][n][cd]
__global__ __launch_bounds__(512) void k_qkvt(
    const float* __restrict__ ft, const float* __restrict__ fi,
    const short* __restrict__ Wb,
    const float* __restrict__ bq, const float* __restrict__ bk,
    const float* __restrict__ bvp, const float* __restrict__ bt,
    short* __restrict__ Qb, short* __restrict__ Kb,
    short* __restrict__ Vb, short* __restrict__ Tb) {
  __shared__ short lt[64 * 256];  // 32 KB, swizzled [n][c]
  __shared__ short li[64 * 256];  // 32 KB

  int tid = threadIdx.x;
  int b = blockIdx.x >> 6, nt = blockIdx.x & 63;
  int n0 = nt * 64;

  // ---- stage both tiles transposed (read coalesced along n, write [n][c])
#pragma unroll
  for (int t = 0; t < 2; ++t) {
    const float* src = (t == 0 ? ft : fi) + (size_t)b * CIN * NPIX + n0;
    short* dst = (t == 0) ? lt : li;
#pragma unroll
    for (int it = 0; it < 8; ++it) {
      int id = it * 512 + tid;     // 0..4095 chunks of 4 c-values
      int n = id & 63, cg = id >> 6;
      int c0 = cg * 4;
      float x0 = src[(size_t)(c0 + 0) * NPIX + n];
      float x1 = src[(size_t)(c0 + 1) * NPIX + n];
      float x2 = src[(size_t)(c0 + 2) * NPIX + n];
      float x3 = src[(size_t)(c0 + 3) * NPIX + n];
      s16x4 v;
      v.x = f2bf(x0); v.y = f2bf(x1); v.z = f2bf(x2); v.w = f2bf(x3);
      int di = n * 256 + ((((c0 >> 3) ^ (n & 7)) << 3)) + (c0 & 7);
      *(s16x4*)&dst[di] = v;
    }
  }
  __syncthreads();

  int w = tid >> 6, lane = tid & 63;
  int lr = lane & 15, hg = lane >> 4;
  int op = w >> 1, half = w & 1;  // op: 0=Q 1=K 2=V 3=T

  const short* X = (op == 1 || op == 2) ? li : lt;
  const short* W = Wb + op * (CD * CIN);

  f32x4 acc[4][4] = {};

  if (op != 2) {
    // ---- Q/K/T: D[n][cd]
#pragma unroll
    for (int ks = 0; ks < 8; ++ks) {
      s16x8 a[4];
#pragma unroll
      for (int ni = 0; ni < 4; ++ni) {
        int row = ni * 16 + lr;
        int di = row * 256 + (((ks * 4 + hg) ^ (row & 7)) << 3);
        a[ni] = *(const s16x8*)&X[di];
      }
#pragma unroll
      for (int cj = 0; cj < 4; ++cj) {
        int cd = half * 64 + cj * 16 + lr;
        s16x8 bfr = *(const s16x8*)&W[cd * CIN + ks * 32 + hg * 8];
#pragma unroll
        for (int ni = 0; ni < 4; ++ni) acc[ni][cj] = MFMA(a[ni], bfr, acc[ni][cj]);
      }
    }
    const float* bias = (op == 0) ? bq : (op == 1) ? bk : bt;
    short* out = (op == 0) ? Qb : (op == 1) ? Kb : Tb;
    float scl = (op == 0) ? 0.08838834764831843f : 1.0f;
#pragma unroll
    for (int cj = 0; cj < 4; ++cj) {
      int cd = half * 64 + cj * 16 + lr;
      float bb = bias[cd];
#pragma unroll
      for (int ni = 0; ni < 4; ++ni)
#pragma unroll
        for (int r = 0; r < 4; ++r) {
          int row = n0 + ni * 16 + hg * 4 + r;
          out[((size_t)b * NPIX + row) * CD + cd] = f2bf((acc[ni][cj][r] + bb) * scl);
        }
    }
  } else {
    // ---- V: D[cd][n]
#pragma unroll
    for (int ks = 0; ks < 8; ++ks) {
      s16x8 bx[4];
#pragma unroll
      for (int nj = 0; nj < 4; ++nj) {
        int row = nj * 16 + lr;
        int di = row * 256 + (((ks * 4 + hg) ^ (row & 7)) << 3);
        bx[nj] = *(const s16x8*)&X[di];
      }
#pragma unroll
      for (int ci = 0; ci < 4; ++ci) {
        int cd = half * 64 + ci * 16 + lr;
        s16x8 aw = *(const s16x8*)&W[cd * CIN + ks * 32 + hg * 8];
#pragma unroll
        for (int nj = 0; nj < 4; ++nj) acc[ci][nj] = MFMA(aw, bx[nj], acc[ci][nj]);
      }
    }
#pragma unroll
    for (int ci = 0; ci < 4; ++ci)
#pragma unroll
      for (int r = 0; r < 4; ++r) {
        int cd = half * 64 + ci * 16 + hg * 4 + r;
        float bb = bvp[cd];
#pragma unroll
        for (int nj = 0; nj < 4; ++nj) {
          int col = n0 + nj * 16 + lr;
          Vb[((size_t)b * CD + cd) * NPIX + col] = f2bf(acc[ci][nj][r] + bb);
        }
      }
  }
}

// ---------------------------------------------------------------- kernel 2
// Flash attention. Block = 256 thr (4 waves), each wave 32 q-rows -> 128 q/block.
// Grid = 256; bid&7 = batch so each batch's K/V stays on one XCD's L2.
// K/V tiles (64 m) staged in LDS, XOR-swizzled (G4) for conflict-free b128 reads.
__global__ __launch_bounds__(256) void k_attn(
    const short* __restrict__ Qb, const short* __restrict__ Kb,
    const short* __restrict__ Vb, const short* __restrict__ Tb,
    short* __restrict__ Xb) {
  __shared__ short Kl[64 * 128];      // 16 KB  [m][d] swizzled
  __shared__ short Vl[128 * 64];      // 16 KB  [d][m] swizzled
  __shared__ short Pl[4][32 * 72];    // 18 KB  per-wave P buffer, row stride 72

  int tid = threadIdx.x;
  int b = blockIdx.x & 7, qt = blockIdx.x >> 3;  // XCD-affine batch mapping
  int q0 = qt * 128;
  int w = tid >> 6, lane = tid & 63, lr = lane & 15, hg = lane >> 4;

  // Q fragments (Q pre-scaled by 1/sqrt(Cd) in k_qkvt)
  s16x8 qf[2][4];
#pragma unroll
  for (int rs = 0; rs < 2; ++rs)
#pragma unroll
    for (int ks = 0; ks < 4; ++ks)
      qf[rs][ks] = *(const s16x8*)&Qb[((size_t)b * NPIX + q0 + w * 32 + rs * 16 + lr) * CD +
                                      ks * 32 + hg * 8];

  f32x4 o[2][8] = {};
  float mi[2][4], li_[2][4];
#pragma unroll
  for (int rs = 0; rs < 2; ++rs)
#pragma unroll
    for (int r = 0; r < 4; ++r) { mi[rs][r] = -3.0e38f; li_[rs][r] = 0.0f; }

  const float c2 = 1.4426950408889634f;  // log2(e)

  for (int mt = 0; mt < 64; ++mt) {
    int m0 = mt * 64;
    // ---- stage K tile (1024 x 16B chunks)
#pragma unroll
    for (int it = 0; it < 4; ++it) {
      int ch = it * 256 + tid;
      int m = ch >> 4, d2 = ch & 15;
      s16x8 v = *(const s16x8*)&Kb[((size_t)b * NPIX + m0 + m) * CD + d2 * 8];
      int di = (m * 128 + d2 * 8) ^ ((m & 7) << 3);
      *(s16x8*)&Kl[di] = v;
    }
    // ---- stage V tile (1024 x 16B chunks: d 0..127, 8 m-chunks per row)
#pragma unroll
    for (int it = 0; it < 4; ++it) {
      int ch = it * 256 + tid;
      int d = ch >> 3, m2 = ch & 7;
      s16x8 v = *(const s16x8*)&Vb[((size_t)b * CD + d) * NPIX + m0 + m2 * 8];
      int di = (d * 64 + m2 * 8) ^ ((d & 7) << 3);
      *(s16x8*)&Vl[di] = v;
    }
    __syncthreads();

    // ---- S = Q K^T (pre-scaled)
    f32x4 s[2][4] = {};
#pragma unroll
    for (int ks = 0; ks < 4; ++ks)
#pragma unroll
      for (int ct = 0; ct < 4; ++ct) {
        int m = ct * 16 + lr;
        int di = (m * 128 + (ks * 4 + hg) * 8) ^ ((m & 7) << 3);
        s16x8 kb = *(const s16x8*)&Kl[di];
        s[0][ct] = MFMA(qf[0][ks], kb, s[0][ct]);
        s[1][ct] = MFMA(qf[1][ks], kb, s[1][ct]);
      }

    // ---- online softmax (rows live in 16-lane groups; reduce via shfl_xor)
#pragma unroll
    for (int rs = 0; rs < 2; ++rs)
#pragma unroll
      for (int r = 0; r < 4; ++r) {
        float mx = fmaxf(fmaxf(s[rs][0][r], s[rs][1][r]), fmaxf(s[rs][2][r], s[rs][3][r]));
        mx = fmaxf(mx, __shfl_xor(mx, 1));
        mx = fmaxf(mx, __shfl_xor(mx, 2));
        mx = fmaxf(mx, __shfl_xor(mx, 4));
        mx = fmaxf(mx, __shfl_xor(mx, 8));
        float mnew = fmaxf(mi[rs][r], mx);
        float resc = __builtin_amdgcn_exp2f((mi[rs][r] - mnew) * c2);
        mi[rs][r] = mnew;
        float rsum = 0.0f;
#pragma unroll
        for (int ct = 0; ct < 4; ++ct) {
          float p = __builtin_amdgcn_exp2f((s[rs][ct][r] - mnew) * c2);
          s[rs][ct][r] = p;
          rsum += p;
        }
        rsum += __shfl_xor(rsum, 1);
        rsum += __shfl_xor(rsum, 2);
        rsum += __shfl_xor(rsum, 4);
        rsum += __shfl_xor(rsum, 8);
        li_[rs][r] = li_[rs][r] * resc + rsum;
#pragma unroll
        for (int dc = 0; dc < 8; ++dc) o[rs][dc][r] *= resc;
      }

    // ---- P -> per-wave LDS (re-layout for PV A-operand)
#pragma unroll
    for (int rs = 0; rs < 2; ++rs)
#pragma unroll
      for (int ct = 0; ct < 4; ++ct)
#pragma unroll
        for (int r = 0; r < 4; ++r)
          Pl[w][(rs * 16 + hg * 4 + r) * 72 + ct * 16 + lr] = f2bf(s[rs][ct][r]);

    // ---- O += P V
#pragma unroll
    for (int ks2 = 0; ks2 < 2; ++ks2) {
      s16x8 pa[2];
#pragma unroll
      for (int rs = 0; rs < 2; ++rs)
        pa[rs] = *(const s16x8*)&Pl[w][(rs * 16 + lr) * 72 + ks2 * 32 + hg * 8];
#pragma unroll
      for (int dc = 0; dc < 8; ++dc) {
        int d = dc * 16 + lr;
        int di = (d * 64 + (ks2 * 4 + hg) * 8) ^ ((d & 7) << 3);
        s16x8 vb = *(const s16x8*)&Vl[di];
        o[0][dc] = MFMA(pa[0], vb, o[0][dc]);
        o[1][dc] = MFMA(pa[1], vb, o[1][dc]);
      }
    }
    __syncthreads();
  }

  // ---- epilogue: O/l + tproj -> fusedX [b][n][d] bf16
#pragma unroll
  for (int rs = 0; rs < 2; ++rs)
#pragma unroll
    for (int r = 0; r < 4; ++r) {
      float inv = 1.0f / li_[rs][r];
      int row = q0 + w * 32 + rs * 16 + hg * 4 + r;
#pragma unroll
      for (int dc = 0; dc < 8; ++dc) {
        int d = dc * 16 + lr;
        size_t off = ((size_t)b * NPIX + row) * CD + d;
        Xb[off] = f2bf(o[rs][dc][r] * inv + bf2f(Tb[off]));
      }
    }
}

// ---------------------------------------------------------------- kernel 3
// out[b][o][n] = Wf . fusedX + bf   (fp32 out, coalesced 64B stores)
__global__ __launch_bounds__(256) void k_out(
    const short* __restrict__ Wfb, const float* __restrict__ bfp,
    const short* __restrict__ Xb, float* __restrict__ out) {
  int tid = threadIdx.x;
  int b = blockIdx.x >> 6, nt = blockIdx.x & 63, n0 = nt * 64;
  int w = tid >> 6, lane = tid & 63, lr = lane & 15, hg = lane >> 4;

  f32x4 acc[4][4] = {};
#pragma unroll
  for (int ks = 0; ks < 4; ++ks) {
    s16x8 af[4], bx[4];
#pragma unroll
    for (int os = 0; os < 4; ++os)
      af[os] = *(const s16x8*)&Wfb[(w * 64 + os * 16 + lr) * CD + ks * 32 + hg * 8];
#pragma unroll
    for (int nc = 0; nc < 4; ++nc)
      bx[nc] = *(const s16x8*)&Xb[((size_t)b * NPIX + n0 + nc * 16 + lr) * CD + ks * 32 + hg * 8];
#pragma unroll
    for (int os = 0; os < 4; ++os)
#pragma unroll
      for (int nc = 0; nc < 4; ++nc) acc[os][nc] = MFMA(af[os], bx[nc], acc[os][nc]);
  }
#pragma unroll
  for (int os = 0; os < 4; ++os)
#pragma unroll
    for (int r = 0; r < 4; ++r) {
      int oc = w * 64 + os * 16 + hg * 4 + r;
      float bias = bfp[oc];
#pragma unroll
      for (int nc = 0; nc < 4; ++nc) {
        int n = n0 + nc * 16 + lr;
        out[((size_t)b * CIN + oc) * NPIX + n] = acc[os][nc][r] + bias;
      }
    }
}

// ---------------------------------------------------------------- launch
extern "C" void kernel_launch(void* const* d_in, const int* in_sizes, int n_in,
                              void* d_out, int out_size, void* d_ws, size_t ws_size,
                              hipStream_t stream) {
  const float* ft = (const float*)d_in[0];
  const float* fi = (const float*)d_in[1];
  const float* Wq = (const float*)d_in[2];
  const float* bq = (const float*)d_in[3];
  const float* Wk = (const float*)d_in[4];
  const float* bk = (const float*)d_in[5];
  const float* Wv = (const float*)d_in[6];
  const float* bv = (const float*)d_in[7];
  const float* Wt = (const float*)d_in[8];
  const float* bt = (const float*)d_in[9];
  const float* Wf = (const float*)d_in[10];
  const float* bf = (const float*)d_in[11];
  float* out = (float*)d_out;

  // workspace layout (shorts): Qb, Kb, Vb, Tb, Xb (each B*N*CD = 4,194,304),
  // then weights bf16 (4*32768 + 32768). Total ~42.3 MB.
  short* wsS = (short*)d_ws;
  short* Qb = wsS;
  short* Kb = wsS + 4194304;
  short* Vb = wsS + 8388608;
  short* Tb = wsS + 12582912;
  short* Xb = wsS + 16777216;
  short* Wb = wsS + 20971520;

  k_wconv<<<640, 256, 0, stream>>>(Wq, Wk, Wv, Wt, Wf, Wb);
  k_qkvt<<<512, 512, 0, stream>>>(ft, fi, Wb, bq, bk, bv, bt, Qb, Kb, Vb, Tb);
  k_attn<<<256, 256, 0, stream>>>(Qb, Kb, Vb, Tb, Xb);
  k_out<<<512, 256, 0, stream>>>(Wb + 4 * CD * CIN, bf, Xb, out);
}

// Round 3
// 214.632 us; speedup vs baseline: 1.1315x; 1.1315x over previous
//
#include <hip/hip_runtime.h>
#include <hip/hip_bf16.h>

#define BATCH 8
#define CIN 256
#define CD 128
#define NPIX 4096  // 64*64

typedef __attribute__((ext_vector_type(4))) float f32x4;
typedef __attribute__((ext_vector_type(8))) short s16x8;
typedef __attribute__((ext_vector_type(4))) short s16x4;

__device__ __forceinline__ short f2bf(float f) {
  union { float f; unsigned u; } v; v.f = f;
  unsigned r = v.u + 0x7fffu + ((v.u >> 16) & 1u);
  return (short)(r >> 16);
}
__device__ __forceinline__ float bf2f(short s) {
  union { unsigned u; float f; } v; v.u = ((unsigned)(unsigned short)s) << 16;
  return v.f;
}

#define MFMA(a, b, c) __builtin_amdgcn_mfma_f32_16x16x32_bf16((a), (b), (c), 0, 0, 0)

// async global->LDS, 16B per lane; lds dest = wave-uniform base + lane*16
__device__ __forceinline__ void g2l16(const short* g, short* l) {
  __builtin_amdgcn_global_load_lds(
      (const __attribute__((address_space(1))) void*)g,
      (__attribute__((address_space(3))) void*)l, 16, 0, 0);
}

// ---------------------------------------------------------------- kernel 0
__global__ void k_wconv(const float* __restrict__ Wq, const float* __restrict__ Wk,
                        const float* __restrict__ Wv, const float* __restrict__ Wt,
                        const float* __restrict__ Wf, short* __restrict__ out) {
  int idx = blockIdx.x * 256 + threadIdx.x;  // 0..163839
  int region = idx >> 15;
  const float* src = (region == 0) ? Wq : (region == 1) ? Wk : (region == 2) ? Wv
                     : (region == 3) ? Wt : Wf;
  out[idx] = f2bf(src[idx & 32767]);
}

// ---------------------------------------------------------------- kernel 1
// QKVT projection (unchanged from round 1 — 36us combined tail, not the target)
__global__ __launch_bounds__(512) void k_qkvt(
    const float* __restrict__ ft, const float* __restrict__ fi,
    const short* __restrict__ Wb,
    const float* __restrict__ bq, const float* __restrict__ bk,
    const float* __restrict__ bvp, const float* __restrict__ bt,
    short* __restrict__ Qb, short* __restrict__ Kb,
    short* __restrict__ Vb, short* __restrict__ Tb) {
  __shared__ short lt[64 * 256];
  __shared__ short li[64 * 256];

  int tid = threadIdx.x;
  int b = blockIdx.x >> 6, nt = blockIdx.x & 63;
  int n0 = nt * 64;

#pragma unroll
  for (int t = 0; t < 2; ++t) {
    const float* src = (t == 0 ? ft : fi) + (size_t)b * CIN * NPIX + n0;
    short* dst = (t == 0) ? lt : li;
#pragma unroll
    for (int it = 0; it < 8; ++it) {
      int id = it * 512 + tid;
      int n = id & 63, cg = id >> 6;
      int c0 = cg * 4;
      float x0 = src[(size_t)(c0 + 0) * NPIX + n];
      float x1 = src[(size_t)(c0 + 1) * NPIX + n];
      float x2 = src[(size_t)(c0 + 2) * NPIX + n];
      float x3 = src[(size_t)(c0 + 3) * NPIX + n];
      s16x4 v;
      v.x = f2bf(x0); v.y = f2bf(x1); v.z = f2bf(x2); v.w = f2bf(x3);
      int di = n * 256 + ((((c0 >> 3) ^ (n & 7)) << 3)) + (c0 & 7);
      *(s16x4*)&dst[di] = v;
    }
  }
  __syncthreads();

  int w = tid >> 6, lane = tid & 63;
  int lr = lane & 15, hg = lane >> 4;
  int op = w >> 1, half = w & 1;

  const short* X = (op == 1 || op == 2) ? li : lt;
  const short* W = Wb + op * (CD * CIN);

  f32x4 acc[4][4] = {};

  if (op != 2) {
#pragma unroll
    for (int ks = 0; ks < 8; ++ks) {
      s16x8 a[4];
#pragma unroll
      for (int ni = 0; ni < 4; ++ni) {
        int row = ni * 16 + lr;
        int di = row * 256 + (((ks * 4 + hg) ^ (row & 7)) << 3);
        a[ni] = *(const s16x8*)&X[di];
      }
#pragma unroll
      for (int cj = 0; cj < 4; ++cj) {
        int cd = half * 64 + cj * 16 + lr;
        s16x8 bfr = *(const s16x8*)&W[cd * CIN + ks * 32 + hg * 8];
#pragma unroll
        for (int ni = 0; ni < 4; ++ni) acc[ni][cj] = MFMA(a[ni], bfr, acc[ni][cj]);
      }
    }
    const float* bias = (op == 0) ? bq : (op == 1) ? bk : bt;
    short* out = (op == 0) ? Qb : (op == 1) ? Kb : Tb;
    float scl = (op == 0) ? 0.08838834764831843f : 1.0f;
#pragma unroll
    for (int cj = 0; cj < 4; ++cj) {
      int cd = half * 64 + cj * 16 + lr;
      float bb = bias[cd];
#pragma unroll
      for (int ni = 0; ni < 4; ++ni)
#pragma unroll
        for (int r = 0; r < 4; ++r) {
          int row = n0 + ni * 16 + hg * 4 + r;
          out[((size_t)b * NPIX + row) * CD + cd] = f2bf((acc[ni][cj][r] + bb) * scl);
        }
    }
  } else {
#pragma unroll
    for (int ks = 0; ks < 8; ++ks) {
      s16x8 bx[4];
#pragma unroll
      for (int nj = 0; nj < 4; ++nj) {
        int row = nj * 16 + lr;
        int di = row * 256 + (((ks * 4 + hg) ^ (row & 7)) << 3);
        bx[nj] = *(const s16x8*)&X[di];
      }
#pragma unroll
      for (int ci = 0; ci < 4; ++ci) {
        int cd = half * 64 + ci * 16 + lr;
        s16x8 aw = *(const s16x8*)&W[cd * CIN + ks * 32 + hg * 8];
#pragma unroll
        for (int nj = 0; nj < 4; ++nj) acc[ci][nj] = MFMA(aw, bx[nj], acc[ci][nj]);
      }
    }
#pragma unroll
    for (int ci = 0; ci < 4; ++ci)
#pragma unroll
      for (int r = 0; r < 4; ++r) {
        int cd = half * 64 + ci * 16 + hg * 4 + r;
        float bb = bvp[cd];
#pragma unroll
        for (int nj = 0; nj < 4; ++nj) {
          int col = n0 + nj * 16 + lr;
          Vb[((size_t)b * CD + cd) * NPIX + col] = f2bf(acc[ci][nj][r] + bb);
        }
      }
  }
}

// ---------------------------------------------------------------- kernel 2
// Flash attention v2: QBLK=64 (4 waves x 16 q-rows), grid 512 -> 2 blocks/CU.
// Double-buffered K/V via global_load_lds (linear LDS dest, pre-swizzled
// global source = same XOR involution), defer-max softmax, setprio on MFMA.
__global__ __launch_bounds__(256) void k_attn(
    const short* __restrict__ Qb, const short* __restrict__ Kb,
    const short* __restrict__ Vb, const short* __restrict__ Tb,
    short* __restrict__ Xb) {
  __shared__ short Kl[2][64 * 128];   // 2 x 16 KB, [m][d] xor-swizzled
  __shared__ short Vl[2][128 * 64];   // 2 x 16 KB, [d][m] xor-swizzled
  __shared__ short Pl[4][16 * 72];    // 9 KB, per-wave P, row stride 72

  int tid = threadIdx.x;
  int b = blockIdx.x & 7, qt = blockIdx.x >> 3;  // batch -> XCD affinity
  int q0 = qt * 64;
  int w = tid >> 6, lane = tid & 63, lr = lane & 15, hg = lane >> 4;

  // per-lane staging coords: linear LDS granule G holds global granule G^swz
  int km[4], kc[4], vd[4], vc[4];
#pragma unroll
  for (int it = 0; it < 4; ++it) {
    int G = it * 256 + tid;
    int m = G >> 4, gi = G & 15;
    km[it] = m; kc[it] = (gi ^ (m & 7)) * 8;
    int d = G >> 3, g2 = G & 7;
    vd[it] = d; vc[it] = (g2 ^ (d & 7)) * 8;
  }
  int ldsb = (tid & ~63) * 8;  // wave-uniform lane-0 granule offset (shorts/8... *8 shorts)

  const short* Kbb = Kb + (size_t)b * NPIX * CD;
  const short* Vbb = Vb + (size_t)b * CD * NPIX;

  // Q fragments (pre-scaled by 1/sqrt(Cd))
  s16x8 qf[4];
#pragma unroll
  for (int ks = 0; ks < 4; ++ks)
    qf[ks] = *(const s16x8*)&Qb[((size_t)b * NPIX + q0 + w * 16 + lr) * CD + ks * 32 + hg * 8];

  f32x4 o[8] = {};
  float mi[4], li_[4];
#pragma unroll
  for (int r = 0; r < 4; ++r) { mi[r] = -3.0e38f; li_[r] = 0.0f; }

  const float c2 = 1.4426950408889634f;  // log2(e)

  // prologue: stage tile 0 into buf 0
#pragma unroll
  for (int it = 0; it < 4; ++it) {
    g2l16(&Kbb[(size_t)km[it] * CD + kc[it]], &Kl[0][it * 2048 + ldsb]);
    g2l16(&Vbb[(size_t)vd[it] * NPIX + vc[it]], &Vl[0][it * 2048 + ldsb]);
  }
  __syncthreads();

  for (int mt = 0; mt < 64; ++mt) {
    int cur = mt & 1;
    // ---- issue next tile's loads into the other buffer (completes by the
    //      end-of-iteration __syncthreads vmcnt drain; latency hides under compute)
    if (mt < 63) {
      int m1 = (mt + 1) * 64;
#pragma unroll
      for (int it = 0; it < 4; ++it) {
        g2l16(&Kbb[(size_t)(m1 + km[it]) * CD + kc[it]], &Kl[cur ^ 1][it * 2048 + ldsb]);
        g2l16(&Vbb[(size_t)vd[it] * NPIX + m1 + vc[it]], &Vl[cur ^ 1][it * 2048 + ldsb]);
      }
    }

    // ---- S = Q K^T (pre-scaled)
    f32x4 s[4] = {};
    __builtin_amdgcn_s_setprio(1);
#pragma unroll
    for (int ks = 0; ks < 4; ++ks)
#pragma unroll
      for (int ct = 0; ct < 4; ++ct) {
        int m = ct * 16 + lr;
        int di = (m * 128 + (ks * 4 + hg) * 8) ^ ((m & 7) << 3);
        s16x8 kb = *(const s16x8*)&Kl[cur][di];
        s[ct] = MFMA(qf[ks], kb, s[ct]);
      }
    __builtin_amdgcn_s_setprio(0);

    // ---- online softmax with defer-max (THR=8): rescale only when max grows
    float mx[4];
#pragma unroll
    for (int r = 0; r < 4; ++r) {
      float m_ = fmaxf(fmaxf(s[0][r], s[1][r]), fmaxf(s[2][r], s[3][r]));
      m_ = fmaxf(m_, __shfl_xor(m_, 1));
      m_ = fmaxf(m_, __shfl_xor(m_, 2));
      m_ = fmaxf(m_, __shfl_xor(m_, 4));
      m_ = fmaxf(m_, __shfl_xor(m_, 8));
      mx[r] = m_;
    }
    bool grow = (mx[0] > mi[0] + 8.0f) | (mx[1] > mi[1] + 8.0f) |
                (mx[2] > mi[2] + 8.0f) | (mx[3] > mi[3] + 8.0f);
    if (__any(grow)) {
#pragma unroll
      for (int r = 0; r < 4; ++r) {
        float mnew = fmaxf(mi[r], mx[r]);
        float resc = __builtin_amdgcn_exp2f((mi[r] - mnew) * c2);
        mi[r] = mnew;
        li_[r] *= resc;
#pragma unroll
        for (int dc = 0; dc < 8; ++dc) o[dc][r] *= resc;
      }
    }
#pragma unroll
    for (int r = 0; r < 4; ++r) {
      float rsum = 0.0f;
#pragma unroll
      for (int ct = 0; ct < 4; ++ct) {
        float p = __builtin_amdgcn_exp2f((s[ct][r] - mi[r]) * c2);
        s[ct][r] = p;
        rsum += p;
      }
      rsum += __shfl_xor(rsum, 1);
      rsum += __shfl_xor(rsum, 2);
      rsum += __shfl_xor(rsum, 4);
      rsum += __shfl_xor(rsum, 8);
      li_[r] += rsum;
    }

    // ---- P -> per-wave LDS (re-layout for PV A-operand)
#pragma unroll
    for (int ct = 0; ct < 4; ++ct)
#pragma unroll
      for (int r = 0; r < 4; ++r)
        Pl[w][(hg * 4 + r) * 72 + ct * 16 + lr] = f2bf(s[ct][r]);

    // ---- O += P V
    __builtin_amdgcn_s_setprio(1);
#pragma unroll
    for (int ks2 = 0; ks2 < 2; ++ks2) {
      s16x8 pa = *(const s16x8*)&Pl[w][lr * 72 + ks2 * 32 + hg * 8];
#pragma unroll
      for (int dc = 0; dc < 8; ++dc) {
        int d = dc * 16 + lr;
        int di = (d * 64 + (ks2 * 4 + hg) * 8) ^ ((d & 7) << 3);
        s16x8 vb = *(const s16x8*)&Vl[cur][di];
        o[dc] = MFMA(pa, vb, o[dc]);
      }
    }
    __builtin_amdgcn_s_setprio(0);
    __syncthreads();
  }

  // ---- epilogue: O/l + tproj -> fusedX [b][n][d] bf16
#pragma unroll
  for (int r = 0; r < 4; ++r) {
    float inv = 1.0f / li_[r];
    int row = q0 + w * 16 + hg * 4 + r;
#pragma unroll
    for (int dc = 0; dc < 8; ++dc) {
      int d = dc * 16 + lr;
      size_t off = ((size_t)b * NPIX + row) * CD + d;
      Xb[off] = f2bf(o[dc][r] * inv + bf2f(Tb[off]));
    }
  }
}

// ---------------------------------------------------------------- kernel 3
__global__ __launch_bounds__(256) void k_out(
    const short* __restrict__ Wfb, const float* __restrict__ bfp,
    const short* __restrict__ Xb, float* __restrict__ out) {
  int tid = threadIdx.x;
  int b = blockIdx.x >> 6, nt = blockIdx.x & 63, n0 = nt * 64;
  int w = tid >> 6, lane = tid & 63, lr = lane & 15, hg = lane >> 4;

  f32x4 acc[4][4] = {};
#pragma unroll
  for (int ks = 0; ks < 4; ++ks) {
    s16x8 af[4], bx[4];
#pragma unroll
    for (int os = 0; os < 4; ++os)
      af[os] = *(const s16x8*)&Wfb[(w * 64 + os * 16 + lr) * CD + ks * 32 + hg * 8];
#pragma unroll
    for (int nc = 0; nc < 4; ++nc)
      bx[nc] = *(const s16x8*)&Xb[((size_t)b * NPIX + n0 + nc * 16 + lr) * CD + ks * 32 + hg * 8];
#pragma unroll
    for (int os = 0; os < 4; ++os)
#pragma unroll
      for (int nc = 0; nc < 4; ++nc) acc[os][nc] = MFMA(af[os], bx[nc], acc[os][nc]);
  }
#pragma unroll
  for (int os = 0; os < 4; ++os)
#pragma unroll
    for (int r = 0; r < 4; ++r) {
      int oc = w * 64 + os * 16 + hg * 4 + r;
      float bias = bfp[oc];
#pragma unroll
      for (int nc = 0; nc < 4; ++nc) {
        int n = n0 + nc * 16 + lr;
        out[((size_t)b * CIN + oc) * NPIX + n] = acc[os][nc][r] + bias;
      }
    }
}

// ---------------------------------------------------------------- launch
extern "C" void kernel_launch(void* const* d_in, const int* in_sizes, int n_in,
                              void* d_out, int out_size, void* d_ws, size_t ws_size,
                              hipStream_t stream) {
  const float* ft = (const float*)d_in[0];
  const float* fi = (const float*)d_in[1];
  const float* Wq = (const float*)d_in[2];
  const float* bq = (const float*)d_in[3];
  const float* Wk = (const float*)d_in[4];
  const float* bk = (const float*)d_in[5];
  const float* Wv = (const float*)d_in[6];
  const float* bv = (const float*)d_in[7];
  const float* Wt = (const float*)d_in[8];
  const float* bt = (const float*)d_in[9];
  const float* Wf = (const float*)d_in[10];
  const float* bf = (const float*)d_in[11];
  float* out = (float*)d_out;

  short* wsS = (short*)d_ws;
  short* Qb = wsS;
  short* Kb = wsS + 4194304;
  short* Vb = wsS + 8388608;
  short* Tb = wsS + 12582912;
  short* Xb = wsS + 16777216;
  short* Wb = wsS + 20971520;

  k_wconv<<<640, 256, 0, stream>>>(Wq, Wk, Wv, Wt, Wf, Wb);
  k_qkvt<<<512, 512, 0, stream>>>(ft, fi, Wb, bq, bk, bv, bt, Qb, Kb, Vb, Tb);
  k_attn<<<512, 256, 0, stream>>>(Qb, Kb, Vb, Tb, Xb);
  k_out<<<512, 256, 0, stream>>>(Wb + 4 * CD * CIN, bf, Xb, out);
}

// Round 4
// 180.468 us; speedup vs baseline: 1.3457x; 1.1893x over previous
//
#include <hip/hip_runtime.h>
#include <hip/hip_bf16.h>

#define BATCH 8
#define CIN 256
#define CD 128
#define NPIX 4096  // 64*64

typedef __attribute__((ext_vector_type(4))) float f32x4;
typedef __attribute__((ext_vector_type(16))) float f32x16;
typedef __attribute__((ext_vector_type(8))) short s16x8;
typedef __attribute__((ext_vector_type(4))) short s16x4;

__device__ __forceinline__ short f2bf(float f) {
  union { float f; unsigned u; } v; v.f = f;
  unsigned r = v.u + 0x7fffu + ((v.u >> 16) & 1u);
  return (short)(r >> 16);
}
__device__ __forceinline__ float bf2f(short s) {
  union { unsigned u; float f; } v; v.u = ((unsigned)(unsigned short)s) << 16;
  return v.f;
}
// v_cvt_pk_bf16_f32: d = {bf16(a) lo16, bf16(b) hi16}  (T12 recipe)
__device__ __forceinline__ unsigned pkbf(float a, float b) {
  unsigned r;
  asm("v_cvt_pk_bf16_f32 %0, %1, %2" : "=v"(r) : "v"(a), "v"(b));
  return r;
}

#define MFMA(a, b, c) __builtin_amdgcn_mfma_f32_16x16x32_bf16((a), (b), (c), 0, 0, 0)
#define MFMA32(a, b, c) __builtin_amdgcn_mfma_f32_32x32x16_bf16((a), (b), (c), 0, 0, 0)

// async global->LDS, 16B per lane; lds dest = wave-uniform base + lane*16
__device__ __forceinline__ void g2l16(const short* g, short* l) {
  __builtin_amdgcn_global_load_lds(
      (const __attribute__((address_space(1))) void*)g,
      (__attribute__((address_space(3))) void*)l, 16, 0, 0);
}

// ---------------------------------------------------------------- kernel 0
__global__ void k_wconv(const float* __restrict__ Wq, const float* __restrict__ Wk,
                        const float* __restrict__ Wv, const float* __restrict__ Wt,
                        const float* __restrict__ Wf, short* __restrict__ out) {
  int idx = blockIdx.x * 256 + threadIdx.x;  // 0..163839
  int region = idx >> 15;
  const float* src = (region == 0) ? Wq : (region == 1) ? Wk : (region == 2) ? Wv
                     : (region == 3) ? Wt : Wf;
  out[idx] = f2bf(src[idx & 32767]);
}

// ---------------------------------------------------------------- kernel 1
// QKVT projection (unchanged — not the current target)
__global__ __launch_bounds__(512) void k_qkvt(
    const float* __restrict__ ft, const float* __restrict__ fi,
    const short* __restrict__ Wb,
    const float* __restrict__ bq, const float* __restrict__ bk,
    const float* __restrict__ bvp, const float* __restrict__ bt,
    short* __restrict__ Qb, short* __restrict__ Kb,
    short* __restrict__ Vb, short* __restrict__ Tb) {
  __shared__ short lt[64 * 256];
  __shared__ short li[64 * 256];

  int tid = threadIdx.x;
  int b = blockIdx.x >> 6, nt = blockIdx.x & 63;
  int n0 = nt * 64;

#pragma unroll
  for (int t = 0; t < 2; ++t) {
    const float* src = (t == 0 ? ft : fi) + (size_t)b * CIN * NPIX + n0;
    short* dst = (t == 0) ? lt : li;
#pragma unroll
    for (int it = 0; it < 8; ++it) {
      int id = it * 512 + tid;
      int n = id & 63, cg = id >> 6;
      int c0 = cg * 4;
      float x0 = src[(size_t)(c0 + 0) * NPIX + n];
      float x1 = src[(size_t)(c0 + 1) * NPIX + n];
      float x2 = src[(size_t)(c0 + 2) * NPIX + n];
      float x3 = src[(size_t)(c0 + 3) * NPIX + n];
      s16x4 v;
      v.x = f2bf(x0); v.y = f2bf(x1); v.z = f2bf(x2); v.w = f2bf(x3);
      int di = n * 256 + ((((c0 >> 3) ^ (n & 7)) << 3)) + (c0 & 7);
      *(s16x4*)&dst[di] = v;
    }
  }
  __syncthreads();

  int w = tid >> 6, lane = tid & 63;
  int lr = lane & 15, hg = lane >> 4;
  int op = w >> 1, half = w & 1;

  const short* X = (op == 1 || op == 2) ? li : lt;
  const short* W = Wb + op * (CD * CIN);

  f32x4 acc[4][4] = {};

  if (op != 2) {
#pragma unroll
    for (int ks = 0; ks < 8; ++ks) {
      s16x8 a[4];
#pragma unroll
      for (int ni = 0; ni < 4; ++ni) {
        int row = ni * 16 + lr;
        int di = row * 256 + (((ks * 4 + hg) ^ (row & 7)) << 3);
        a[ni] = *(const s16x8*)&X[di];
      }
#pragma unroll
      for (int cj = 0; cj < 4; ++cj) {
        int cd = half * 64 + cj * 16 + lr;
        s16x8 bfr = *(const s16x8*)&W[cd * CIN + ks * 32 + hg * 8];
#pragma unroll
        for (int ni = 0; ni < 4; ++ni) acc[ni][cj] = MFMA(a[ni], bfr, acc[ni][cj]);
      }
    }
    const float* bias = (op == 0) ? bq : (op == 1) ? bk : bt;
    short* out = (op == 0) ? Qb : (op == 1) ? Kb : Tb;
    float scl = (op == 0) ? 0.08838834764831843f : 1.0f;
#pragma unroll
    for (int cj = 0; cj < 4; ++cj) {
      int cd = half * 64 + cj * 16 + lr;
      float bb = bias[cd];
#pragma unroll
      for (int ni = 0; ni < 4; ++ni)
#pragma unroll
        for (int r = 0; r < 4; ++r) {
          int row = n0 + ni * 16 + hg * 4 + r;
          out[((size_t)b * NPIX + row) * CD + cd] = f2bf((acc[ni][cj][r] + bb) * scl);
        }
    }
  } else {
#pragma unroll
    for (int ks = 0; ks < 8; ++ks) {
      s16x8 bx[4];
#pragma unroll
      for (int nj = 0; nj < 4; ++nj) {
        int row = nj * 16 + lr;
        int di = row * 256 + (((ks * 4 + hg) ^ (row & 7)) << 3);
        bx[nj] = *(const s16x8*)&X[di];
      }
#pragma unroll
      for (int ci = 0; ci < 4; ++ci) {
        int cd = half * 64 + ci * 16 + lr;
        s16x8 aw = *(const s16x8*)&W[cd * CIN + ks * 32 + hg * 8];
#pragma unroll
        for (int nj = 0; nj < 4; ++nj) acc[ci][nj] = MFMA(aw, bx[nj], acc[ci][nj]);
      }
    }
#pragma unroll
    for (int ci = 0; ci < 4; ++ci)
#pragma unroll
      for (int r = 0; r < 4; ++r) {
        int cd = half * 64 + ci * 16 + hg * 4 + r;
        float bb = bvp[cd];
#pragma unroll
        for (int nj = 0; nj < 4; ++nj) {
          int col = n0 + nj * 16 + lr;
          Vb[((size_t)b * CD + cd) * NPIX + col] = f2bf(acc[ci][nj][r] + bb);
        }
      }
  }
}

// ---------------------------------------------------------------- kernel 2
// Flash attention v3: 32x32 MFMA, swapped operands. 4 waves x 32 q-rows
// (QBLK=128), grid 256 (1 block/CU, bid&7 = batch -> XCD affinity).
// S^T = K.Q^T so each lane owns ONE q-row: softmax = in-lane tree + one
// shfl_xor(32). P stays in registers (cvt_pk + lane^32 exchange) and feeds
// PV (O^T = V^T.P^T) directly. K/V double-buffered via global_load_lds with
// pre-swizzled global source.
__global__ __launch_bounds__(256) void k_attn(
    const short* __restrict__ Qb, const short* __restrict__ Kb,
    const short* __restrict__ Vb, const short* __restrict__ Tb,
    short* __restrict__ Xb) {
  __shared__ short Kl[2][64 * 128];   // [m][d], xor-swizzled, 2 x 16 KB
  __shared__ short Vl[2][128 * 64];   // [d][m], xor-swizzled, 2 x 16 KB

  int tid = threadIdx.x;
  int b = blockIdx.x & 7, qt = blockIdx.x >> 3;
  int q0 = qt * 128;
  int w = tid >> 6, lane = tid & 63;
  int l31 = lane & 31, h = lane >> 5;

  // staging coords: linear LDS granule G holds global granule with swizzled col
  int km[4], kc[4], vd[4], vc[4];
#pragma unroll
  for (int it = 0; it < 4; ++it) {
    int G = it * 256 + tid;
    int m = G >> 4, gi = G & 15;
    km[it] = m; kc[it] = (gi ^ (m & 7)) * 8;
    int d = G >> 3, g2 = G & 7;
    vd[it] = d; vc[it] = (g2 ^ (d & 7)) * 8;
  }
  int ldsb = (tid & ~63) * 8;  // wave-uniform granule base (shorts)

  const short* Kbb = Kb + (size_t)b * NPIX * CD;
  const short* Vbb = Vb + (size_t)b * CD * NPIX;

  // Q fragments: lane holds Q[q = q0+w*32+l31][d = ks*16 + h*8 .. +8]
  s16x8 qf[8];
  const short* qrow = &Qb[((size_t)b * NPIX + q0 + w * 32 + l31) * CD];
#pragma unroll
  for (int ks = 0; ks < 8; ++ks) qf[ks] = *(const s16x8*)&qrow[ks * 16 + h * 8];

  f32x16 o[4] = {};          // O^T: d = dc*32 + (r&3)+8*(r>>2)+4h, q = l31
  float mi = 0.0f, li = 0.0f;  // scalars: one q-row per lane
  const float c2 = 1.4426950408889634f;

  // prologue: stage tile 0 into buf 0
#pragma unroll
  for (int it = 0; it < 4; ++it) {
    g2l16(&Kbb[(size_t)km[it] * CD + kc[it]], &Kl[0][it * 2048 + ldsb]);
    g2l16(&Vbb[(size_t)vd[it] * NPIX + vc[it]], &Vl[0][it * 2048 + ldsb]);
  }
  __syncthreads();

  for (int mt = 0; mt < 64; ++mt) {
    int cur = mt & 1;
    if (mt < 63) {
      int m1 = (mt + 1) * 64;
#pragma unroll
      for (int it = 0; it < 4; ++it) {
        g2l16(&Kbb[(size_t)(m1 + km[it]) * CD + kc[it]], &Kl[cur ^ 1][it * 2048 + ldsb]);
        g2l16(&Vbb[(size_t)vd[it] * NPIX + m1 + vc[it]], &Vl[cur ^ 1][it * 2048 + ldsb]);
      }
    }

    // ---- S^T = K . Q^T : sp[mt2] reg r -> S[m = mt2*32+(r&3)+8*(r>>2)+4h][q=l31]
    f32x16 sp0 = {}, sp1 = {};
    __builtin_amdgcn_s_setprio(1);
#pragma unroll
    for (int ks = 0; ks < 8; ++ks) {
      int g = (ks * 2 + h) * 8;
      s16x8 ka0 = *(const s16x8*)&Kl[cur][(l31 * 128 + g) ^ ((l31 & 7) << 3)];
      s16x8 ka1 = *(const s16x8*)&Kl[cur][((32 + l31) * 128 + g) ^ ((l31 & 7) << 3)];
      sp0 = MFMA32(ka0, qf[ks], sp0);
      sp1 = MFMA32(ka1, qf[ks], sp1);
    }
    __builtin_amdgcn_s_setprio(0);

    // ---- softmax (defer-max, THR=8, mi init 0): in-lane tree + one shfl
    float ta[16];
#pragma unroll
    for (int i = 0; i < 16; ++i) ta[i] = fmaxf(sp0[i], sp1[i]);
#pragma unroll
    for (int s2 = 8; s2 >= 1; s2 >>= 1)
#pragma unroll
      for (int i = 0; i < 8; ++i)
        if (i < s2) ta[i] = fmaxf(ta[i], ta[i + s2]);
    float mx = fmaxf(ta[0], __shfl_xor(ta[0], 32));
    if (__any(mx > mi + 8.0f)) {  // cold path (never taken for this data)
      float mnew = fmaxf(mi, mx);
      float resc = __builtin_amdgcn_exp2f((mi - mnew) * c2);
      mi = mnew;
      li *= resc;
#pragma unroll
      for (int dc = 0; dc < 4; ++dc)
#pragma unroll
        for (int r = 0; r < 16; ++r) o[dc][r] *= resc;
    }
    float mic2 = mi * c2;
#pragma unroll
    for (int r = 0; r < 16; ++r) {
      sp0[r] = __builtin_amdgcn_exp2f(sp0[r] * c2 - mic2);
      sp1[r] = __builtin_amdgcn_exp2f(sp1[r] * c2 - mic2);
    }
    float sa[16];
#pragma unroll
    for (int i = 0; i < 16; ++i) sa[i] = sp0[i] + sp1[i];
#pragma unroll
    for (int s2 = 8; s2 >= 1; s2 >>= 1)
#pragma unroll
      for (int i = 0; i < 8; ++i)
        if (i < s2) sa[i] += sa[i + s2];
    li += sa[0] + __shfl_xor(sa[0], 32);

    // ---- P -> bf16 PV B-frags, in-register (quad rr of tile mt2 -> frag
    //      ms = mt2*2 + (rr>>1), owned by lane-half th = rr&1)
    s16x8 pb[4];
#pragma unroll
    for (int mt2 = 0; mt2 < 2; ++mt2)
#pragma unroll
      for (int t = 0; t < 2; ++t) {
        float e0, e1, e2, e3, e4, e5, e6, e7;
        if (mt2 == 0) {
          e0 = sp0[8 * t + 0]; e1 = sp0[8 * t + 1]; e2 = sp0[8 * t + 2]; e3 = sp0[8 * t + 3];
          e4 = sp0[8 * t + 4]; e5 = sp0[8 * t + 5]; e6 = sp0[8 * t + 6]; e7 = sp0[8 * t + 7];
        } else {
          e0 = sp1[8 * t + 0]; e1 = sp1[8 * t + 1]; e2 = sp1[8 * t + 2]; e3 = sp1[8 * t + 3];
          e4 = sp1[8 * t + 4]; e5 = sp1[8 * t + 5]; e6 = sp1[8 * t + 6]; e7 = sp1[8 * t + 7];
        }
        unsigned lo0 = pkbf(e0, e1), hi0 = pkbf(e2, e3);   // quad rr=2t   (target h=0)
        unsigned lo1 = pkbf(e4, e5), hi1 = pkbf(e6, e7);   // quad rr=2t+1 (target h=1)
        unsigned slo = h ? lo0 : lo1, shi = h ? hi0 : hi1;  // what partner needs
        unsigned klo = h ? lo1 : lo0, khi = h ? hi1 : hi0;  // what I keep
        unsigned rlo = __shfl_xor(slo, 32), rhi = __shfl_xor(shi, 32);
        union { unsigned u[4]; s16x8 v; } pu;
        pu.u[0] = h ? rlo : klo;   // j0..1 (h_src=0)
        pu.u[1] = h ? rhi : khi;   // j2..3
        pu.u[2] = h ? klo : rlo;   // j4..5 (h_src=1)
        pu.u[3] = h ? khi : rhi;   // j6..7
        pb[mt2 * 2 + t] = pu.v;
      }

    // ---- O^T += V^T . P^T
    __builtin_amdgcn_s_setprio(1);
#pragma unroll
    for (int ms = 0; ms < 4; ++ms) {
      int g = (ms * 2 + h) * 8;
#pragma unroll
      for (int dc = 0; dc < 4; ++dc) {
        int d = dc * 32 + l31;
        s16x8 av = *(const s16x8*)&Vl[cur][(d * 64 + g) ^ ((d & 7) << 3)];
        o[dc] = MFMA32(av, pb[ms], o[dc]);
      }
    }
    __builtin_amdgcn_s_setprio(0);
    __syncthreads();
  }

  // ---- epilogue: O/li + tproj -> fusedX [b][n][d] bf16 (paired u32 stores)
  float inv = 1.0f / li;
  size_t rowOff = ((size_t)b * NPIX + q0 + w * 32 + l31) * CD;
#pragma unroll
  for (int dc = 0; dc < 4; ++dc)
#pragma unroll
    for (int rr = 0; rr < 4; ++rr)
#pragma unroll
      for (int c = 0; c < 4; c += 2) {
        int r = rr * 4 + c;
        int d = dc * 32 + rr * 8 + h * 4 + c;
        size_t off = rowOff + d;
        unsigned tp = *(const unsigned*)&Tb[off];
        float f0 = o[dc][r] * inv + bf2f((short)(tp & 0xffffu));
        float f1 = o[dc][r + 1] * inv + bf2f((short)(tp >> 16));
        *(unsigned*)&Xb[off] = pkbf(f0, f1);
      }
}

// ---------------------------------------------------------------- kernel 3
__global__ __launch_bounds__(256) void k_out(
    const short* __restrict__ Wfb, const float* __restrict__ bfp,
    const short* __restrict__ Xb, float* __restrict__ out) {
  int tid = threadIdx.x;
  int b = blockIdx.x >> 6, nt = blockIdx.x & 63, n0 = nt * 64;
  int w = tid >> 6, lane = tid & 63, lr = lane & 15, hg = lane >> 4;

  f32x4 acc[4][4] = {};
#pragma unroll
  for (int ks = 0; ks < 4; ++ks) {
    s16x8 af[4], bx[4];
#pragma unroll
    for (int os = 0; os < 4; ++os)
      af[os] = *(const s16x8*)&Wfb[(w * 64 + os * 16 + lr) * CD + ks * 32 + hg * 8];
#pragma unroll
    for (int nc = 0; nc < 4; ++nc)
      bx[nc] = *(const s16x8*)&Xb[((size_t)b * NPIX + n0 + nc * 16 + lr) * CD + ks * 32 + hg * 8];
#pragma unroll
    for (int os = 0; os < 4; ++os)
#pragma unroll
      for (int nc = 0; nc < 4; ++nc) acc[os][nc] = MFMA(af[os], bx[nc], acc[os][nc]);
  }
#pragma unroll
  for (int os = 0; os < 4; ++os)
#pragma unroll
    for (int r = 0; r < 4; ++r) {
      int oc = w * 64 + os * 16 + hg * 4 + r;
      float bias = bfp[oc];
#pragma unroll
      for (int nc = 0; nc < 4; ++nc) {
        int n = n0 + nc * 16 + lr;
        out[((size_t)b * CIN + oc) * NPIX + n] = acc[os][nc][r] + bias;
      }
    }
}

// ---------------------------------------------------------------- launch
extern "C" void kernel_launch(void* const* d_in, const int* in_sizes, int n_in,
                              void* d_out, int out_size, void* d_ws, size_t ws_size,
                              hipStream_t stream) {
  const float* ft = (const float*)d_in[0];
  const float* fi = (const float*)d_in[1];
  const float* Wq = (const float*)d_in[2];
  const float* bq = (const float*)d_in[3];
  const float* Wk = (const float*)d_in[4];
  const float* bk = (const float*)d_in[5];
  const float* Wv = (const float*)d_in[6];
  const float* bv = (const float*)d_in[7];
  const float* Wt = (const float*)d_in[8];
  const float* bt = (const float*)d_in[9];
  const float* Wf = (const float*)d_in[10];
  const float* bf = (const float*)d_in[11];
  float* out = (float*)d_out;

  short* wsS = (short*)d_ws;
  short* Qb = wsS;
  short* Kb = wsS + 4194304;
  short* Vb = wsS + 8388608;
  short* Tb = wsS + 12582912;
  short* Xb = wsS + 16777216;
  short* Wb = wsS + 20971520;

  k_wconv<<<640, 256, 0, stream>>>(Wq, Wk, Wv, Wt, Wf, Wb);
  k_qkvt<<<512, 512, 0, stream>>>(ft, fi, Wb, bq, bk, bv, bt, Qb, Kb, Vb, Tb);
  k_attn<<<256, 256, 0, stream>>>(Qb, Kb, Vb, Tb, Xb);
  k_out<<<512, 256, 0, stream>>>(Wb + 4 * CD * CIN, bf, Xb, out);
}